// Round 6
// baseline (81.656 us; speedup 1.0000x reference)
//
#include <hip/hip_runtime.h>
#include <math.h>

// PCEN: EMA over time (s=0.025) + (x/(M+eps)^0.98 + 2)^0.5 - 2^0.5
// x: [B=32, T=8192, F=128] f32 -> out same shape f32.
//
// Exact 3-pass chunked scan. EMA over a chunk of C=32 is affine:
// M_end = a^32 * M_start + q, q = init-0 EMA of the chunk.
//   K1: per (b,chunk,f) compute q -> ws           [streams x once]
//   K2: per (b,f) WAVE-PARALLEL scan of 256 chunk carries (constant-mult
//       affine scan => weighted Hillis-Steele shuffle scan, 6 steps)
//   K3: per (b,chunk,f) exact in-chunk EMA from carry + PCEN epilogue
//       [x re-read is L3-resident; nontemporal out stores keep x resident]
//
// R5 -> R6: K1/K3 stream with 8-deep rotating prefetch instead of holding
// the whole 64-VGPR chunk (occupancy 5->8 waves/SIMD); K2 was 64 waves of
// serial stride-512B loads (latency chain on an empty machine) -> 4096-wave
// shuffle scan.

#define BB 32
#define TT 8192
#define FF 128
#define CC 32            // chunk length
#define KC (TT / CC)     // 256 chunks per chain
#define AA 0.975f
#define SS 0.025f

using f32x2 = __attribute__((ext_vector_type(2))) float;

constexpr float powf_n(float a, int n) {
    float p = 1.0f;
    for (int i = 0; i < n; ++i) p *= a;
    return p;
}
constexpr float P32  = powf_n(0.975f, 32);   // chunk multiplier
constexpr float P128 = powf_n(0.975f, 128);  // per-lane (4 chunks) multiplier

__device__ __forceinline__ float pcen_out(float xv, float m) {
    // (m+eps)^(-0.98) via v_log_f32 / v_exp_f32
    float p = __builtin_amdgcn_exp2f(-0.98f * __builtin_amdgcn_logf(m + 1e-6f));
    return sqrtf(fmaf(xv, p, 2.0f)) - 1.41421356237309505f;
}

// ---- K1: per-chunk init-0 EMA partial q (chunk 0: true value, init x[0]) ----
__global__ __launch_bounds__(256) void pcen_k1(const float* __restrict__ x,
                                               float* __restrict__ q) {
    const int tid = threadIdx.x;
    const int row = blockIdx.x * 4 + (tid >> 6);   // b*KC + k
    const int b   = row >> 8;
    const int k   = row & (KC - 1);
    const int f2  = tid & 63;

    const f32x2* xp = (const f32x2*)(x + ((size_t)b * TT + (size_t)k * CC) * FF) + f2;

    f32x2 v[8];
    #pragma unroll
    for (int u = 0; u < 8; ++u) v[u] = xp[(size_t)u * (FF / 2)];

    float m0 = (k == 0) ? v[0][0] : SS * v[0][0];
    float m1 = (k == 0) ? v[0][1] : SS * v[0][1];

    #pragma unroll
    for (int jb = 0; jb < CC; jb += 8) {
        f32x2 w[8];
        #pragma unroll
        for (int u = 0; u < 8; ++u) w[u] = v[u];
        if (jb + 8 < CC) {
            #pragma unroll
            for (int u = 0; u < 8; ++u) v[u] = xp[(size_t)(jb + 8 + u) * (FF / 2)];
        }
        #pragma unroll
        for (int u = 0; u < 8; ++u) {
            if (jb == 0 && u == 0) continue;  // consumed by init
            m0 = fmaf(AA, m0, SS * w[u][0]);
            m1 = fmaf(AA, m1, SS * w[u][1]);
        }
    }

    f32x2 o; o[0] = m0; o[1] = m1;
    *((f32x2*)(q + ((size_t)b * KC + k) * FF) + f2) = o;
}

// ---- K2: wave-parallel affine scan; q[b][k][f] -> M_start[b][k][f] ----
// I_{-1}=0; I_k = P32*I_{k-1} + q_k; M_start[k] = I_{k-1}.
// (q[0] already holds the TRUE end-of-chunk-0 M, so no special case.)
__global__ __launch_bounds__(256) void pcen_k2(float* __restrict__ q) {
    const int gid  = blockIdx.x * 256 + threadIdx.x;
    const int wid  = gid >> 6;                 // wave id = b*FF + f, 0..4095
    const int lane = threadIdx.x & 63;
    const int b    = wid >> 7;
    const int f    = wid & (FF - 1);
    float* qp = q + (size_t)b * KC * FF + f;

    // lane handles chunks 4*lane .. 4*lane+3
    const int k0 = 4 * lane;
    float t0 = qp[(size_t)(k0 + 0) * FF];
    float t1 = qp[(size_t)(k0 + 1) * FF];
    float t2 = qp[(size_t)(k0 + 2) * FF];
    float t3 = qp[(size_t)(k0 + 3) * FF];

    // local inclusive over the 4 chunks (init 0)
    float v = fmaf(fmaf(fmaf(t0, P32, t1), P32, t2), P32, t3);

    // weighted Hillis-Steele over lanes: v_l += P128^d * v_{l-d}
    float fac = P128;
    #pragma unroll
    for (int d = 1; d < 64; d <<= 1) {
        float up = __shfl_up(v, d, 64);
        if (lane >= d) v = fmaf(fac, up, v);
        fac *= fac;
    }

    // exclusive prefix for this lane = inclusive of lane-1 = I_{k0-1}
    float I = __shfl_up(v, 1, 64);
    if (lane == 0) I = 0.0f;

    qp[(size_t)(k0 + 0) * FF] = I; I = fmaf(P32, I, t0);
    qp[(size_t)(k0 + 1) * FF] = I; I = fmaf(P32, I, t1);
    qp[(size_t)(k0 + 2) * FF] = I; I = fmaf(P32, I, t2);
    qp[(size_t)(k0 + 3) * FF] = I;
}

// ---- K3: exact in-chunk EMA from M_start + PCEN output ----
__global__ __launch_bounds__(256) void pcen_k3(const float* __restrict__ x,
                                               const float* __restrict__ q,
                                               float* __restrict__ out) {
    const int tid = threadIdx.x;
    const int row = blockIdx.x * 4 + (tid >> 6);
    const int b   = row >> 8;
    const int k   = row & (KC - 1);
    const int f2  = tid & 63;

    const size_t base = ((size_t)b * TT + (size_t)k * CC) * FF;
    const f32x2* xp = (const f32x2*)(x + base) + f2;
    f32x2*       op = (f32x2*)(out + base) + f2;

    f32x2 v[8];
    #pragma unroll
    for (int u = 0; u < 8; ++u) v[u] = xp[(size_t)u * (FF / 2)];

    float m0, m1;
    if (k == 0) {
        m0 = v[0][0]; m1 = v[0][1];                        // M[0] = x[0]
    } else {
        const f32x2 mn = *((const f32x2*)(q + ((size_t)b * KC + k) * FF) + f2);
        m0 = fmaf(AA, mn[0], SS * v[0][0]);
        m1 = fmaf(AA, mn[1], SS * v[0][1]);
    }

    #pragma unroll
    for (int jb = 0; jb < CC; jb += 8) {
        f32x2 w[8];
        #pragma unroll
        for (int u = 0; u < 8; ++u) w[u] = v[u];
        if (jb + 8 < CC) {
            #pragma unroll
            for (int u = 0; u < 8; ++u) v[u] = xp[(size_t)(jb + 8 + u) * (FF / 2)];
        }
        #pragma unroll
        for (int u = 0; u < 8; ++u) {
            if (!(jb == 0 && u == 0)) {
                m0 = fmaf(AA, m0, SS * w[u][0]);
                m1 = fmaf(AA, m1, SS * w[u][1]);
            }
            f32x2 o;
            o[0] = pcen_out(w[u][0], m0);
            o[1] = pcen_out(w[u][1], m1);
            __builtin_nontemporal_store(o, op + (size_t)(jb + u) * (FF / 2));
        }
    }
}

// ---- fallback (ws too small): R2-style warm-up kernel, known-good ----
__global__ __launch_bounds__(128) void pcen_fallback(const float* __restrict__ x,
                                                     float* __restrict__ out) {
    const int job = blockIdx.x;
    const int b   = job >> 5;
    const int k   = job & 31;
    const int f   = threadIdx.x;
    const int t0  = k * 256;
    const size_t base = ((size_t)b * TT + t0) * FF + f;
    const float* xp = x + base;
    float*       op = out + base;
    float m;
    if (k == 0) {
        float xv = xp[0];
        m = xv;
        op[0] = pcen_out(xv, m);
    } else {
        const float* wp = xp - (size_t)256 * FF;
        m = wp[0];
        #pragma unroll 8
        for (int j = 1; j < 256; ++j) m = fmaf(AA, m, SS * wp[(size_t)j * FF]);
        float xv = xp[0];
        m = fmaf(AA, m, SS * xv);
        op[0] = pcen_out(xv, m);
    }
    #pragma unroll 4
    for (int j = 1; j < 256; ++j) {
        float xv = xp[(size_t)j * FF];
        m = fmaf(AA, m, SS * xv);
        op[(size_t)j * FF] = pcen_out(xv, m);
    }
}

extern "C" void kernel_launch(void* const* d_in, const int* in_sizes, int n_in,
                              void* d_out, int out_size, void* d_ws, size_t ws_size,
                              hipStream_t stream) {
    const float* x = (const float*)d_in[0];
    float* out = (float*)d_out;
    (void)in_sizes; (void)n_in; (void)out_size;

    const size_t q_bytes = (size_t)BB * KC * FF * sizeof(float);  // 4 MB
    if (ws_size >= q_bytes) {
        float* q = (float*)d_ws;
        pcen_k1<<<(BB * KC) / 4, 256, 0, stream>>>(x, q);
        pcen_k2<<<(BB * FF * 64) / 256, 256, 0, stream>>>(q);   // 4096 waves
        pcen_k3<<<(BB * KC) / 4, 256, 0, stream>>>(x, q, out);
    } else {
        pcen_fallback<<<BB * 32, 128, 0, stream>>>(x, out);
    }
}

// Round 7
// 68.358 us; speedup vs baseline: 1.1945x; 1.1945x over previous
//
#include <hip/hip_runtime.h>
#include <math.h>

// PCEN: EMA over time (s=0.025) + (x/(M+eps)^0.98 + 2)^0.5 - 2^0.5
// x: [B=32, T=8192, F=128] f32 -> out same shape f32.
//
// R6 -> R7: 2-pass, NO global scan. EMA forgets: carry into chunk k is
// I_{k-1} = sum_j a^(64(k-1-j)) q_j; truncate at W=6 terms (a^384 ~ 6e-5,
// out err ~1e-4 << 9.5e-2; k<=6 is exact). So:
//   K1: block=(b,chunk of 64 t) computes q via 4 waves x 16-step
//       sub-aggregates + LDS combine -> q[b][k][f] (2 MB).  [reads x 1x HBM]
//   K3: same geometry; x re-read is L3-resident; carry = 6 weighted q reads
//       (L2); exact in-chunk EMA + PCEN; nontemporal out stores keep x in L3.
// No K2 kernel, no flags/atomics, ordering via kernel boundary.

#define BB 32
#define TT 8192
#define FF 128
#define CC 64            // chunk timesteps per block
#define KC (TT / CC)     // 128 chunks per chain
#define SUB 16           // timesteps per thread
#define NH  (CC / SUB)   // 4 sub-chunks (one per wave)
#define WW 6             // look-back window in chunks
#define AA 0.975f
#define SS 0.025f

using f32x2 = __attribute__((ext_vector_type(2))) float;

constexpr float powf_n(float a, int n) {
    float p = 1.0f;
    for (int i = 0; i < n; ++i) p *= a;
    return p;
}
constexpr float P16 = powf_n(0.975f, 16);   // sub-chunk multiplier
// look-back weights: carry = sum_{jj=1..W} P64^(jj-1) * q[k-jj]
constexpr float WQ[WW] = {
    powf_n(0.975f, 0),   powf_n(0.975f, 64),  powf_n(0.975f, 128),
    powf_n(0.975f, 192), powf_n(0.975f, 256), powf_n(0.975f, 320)
};

__device__ __forceinline__ float pcen_out(float xv, float m) {
    // (m+eps)^(-0.98) via v_log_f32 / v_exp_f32
    float p = __builtin_amdgcn_exp2f(-0.98f * __builtin_amdgcn_logf(m + 1e-6f));
    return sqrtf(fmaf(xv, p, 2.0f)) - 1.41421356237309505f;
}

// ---- K1: per-chunk init-0 EMA aggregate q (chunk 0: anchored M[0]=x[0]) ----
__global__ __launch_bounds__(256) void pcen_k1(const float* __restrict__ x,
                                               float* __restrict__ q) {
    __shared__ f32x2 lds[NH][64];
    const int tid = threadIdx.x;
    const int h   = tid >> 6;            // sub-chunk / wave id, 0..3
    const int f2  = tid & 63;
    const int bid = blockIdx.x;          // b*KC + k
    const int b   = bid >> 7;
    const int k   = bid & (KC - 1);

    const f32x2* xp = (const f32x2*)(x + ((size_t)b * TT + (size_t)k * CC
                                          + (size_t)h * SUB) * FF) + f2;
    f32x2 v[SUB];
    #pragma unroll
    for (int i = 0; i < SUB; ++i) v[i] = xp[(size_t)i * (FF / 2)];

    // sub-aggregate: init-0 EMA over 16 steps (anchored for k==0,h==0)
    float s0, s1;
    if (k == 0 && h == 0) { s0 = v[0][0];      s1 = v[0][1]; }
    else                  { s0 = SS * v[0][0]; s1 = SS * v[0][1]; }
    #pragma unroll
    for (int i = 1; i < SUB; ++i) {
        s0 = fmaf(AA, s0, SS * v[i][0]);
        s1 = fmaf(AA, s1, SS * v[i][1]);
    }

    f32x2 sv; sv[0] = s0; sv[1] = s1;
    lds[h][f2] = sv;
    __syncthreads();

    if (h == 0) {
        f32x2 a0 = lds[0][f2], a1 = lds[1][f2], a2 = lds[2][f2], a3 = lds[3][f2];
        f32x2 o;
        o[0] = fmaf(fmaf(fmaf(a0[0], P16, a1[0]), P16, a2[0]), P16, a3[0]);
        o[1] = fmaf(fmaf(fmaf(a0[1], P16, a1[1]), P16, a2[1]), P16, a3[1]);
        *((f32x2*)(q + ((size_t)b * KC + k) * FF) + f2) = o;
    }
}

// ---- K3: carry from W predecessor q's + exact in-chunk EMA + PCEN ----
__global__ __launch_bounds__(256) void pcen_k3(const float* __restrict__ x,
                                               const float* __restrict__ q,
                                               float* __restrict__ out) {
    __shared__ f32x2 lds[NH][64];
    const int tid = threadIdx.x;
    const int h   = tid >> 6;
    const int f2  = tid & 63;
    const int bid = blockIdx.x;
    const int b   = bid >> 7;
    const int k   = bid & (KC - 1);

    const size_t tbase = (size_t)b * TT + (size_t)k * CC + (size_t)h * SUB;
    const f32x2* xp = (const f32x2*)(x + tbase * FF) + f2;
    f32x2*       op = (f32x2*)(out + tbase * FF) + f2;

    f32x2 v[SUB];
    #pragma unroll
    for (int i = 0; i < SUB; ++i) v[i] = xp[(size_t)i * (FF / 2)];

    // carry = sum_{jj=1..min(W,k)} P64^(jj-1) * q[b][k-jj][f]   (per-f2)
    float c0 = 0.0f, c1 = 0.0f;
    {
        const f32x2* qp = (const f32x2*)(q + (size_t)b * KC * FF) + f2;
        #pragma unroll
        for (int jj = 1; jj <= WW; ++jj) {
            if (jj <= k) {
                f32x2 qv = qp[(size_t)(k - jj) * (FF / 2)];
                c0 = fmaf(WQ[jj - 1], qv[0], c0);
                c1 = fmaf(WQ[jj - 1], qv[1], c1);
            }
        }
    }

    // sub-aggregate (shared so higher waves can compose their sub-carry)
    float s0, s1;
    if (k == 0 && h == 0) { s0 = v[0][0];      s1 = v[0][1]; }
    else                  { s0 = SS * v[0][0]; s1 = SS * v[0][1]; }
    #pragma unroll
    for (int i = 1; i < SUB; ++i) {
        s0 = fmaf(AA, s0, SS * v[i][0]);
        s1 = fmaf(AA, s1, SS * v[i][1]);
    }
    f32x2 sv; sv[0] = s0; sv[1] = s1;
    lds[h][f2] = sv;
    __syncthreads();

    // M entering my sub-chunk: m = a^(16h)*carry + sum_{g<h} a^(16(h-1-g)) s_g
    float m0 = c0, m1 = c1;
    for (int g = 0; g < h; ++g) {        // h is wave-uniform, no divergence
        f32x2 sg = lds[g][f2];
        m0 = fmaf(P16, m0, sg[0]);
        m1 = fmaf(P16, m1, sg[1]);
    }

    // output: exact EMA recurrence within my 16 steps + PCEN
    {
        f32x2 o;
        if (k == 0 && h == 0) { m0 = v[0][0]; m1 = v[0][1]; }
        else {
            m0 = fmaf(AA, m0, SS * v[0][0]);
            m1 = fmaf(AA, m1, SS * v[0][1]);
        }
        o[0] = pcen_out(v[0][0], m0);
        o[1] = pcen_out(v[0][1], m1);
        __builtin_nontemporal_store(o, op);
    }
    #pragma unroll
    for (int i = 1; i < SUB; ++i) {
        m0 = fmaf(AA, m0, SS * v[i][0]);
        m1 = fmaf(AA, m1, SS * v[i][1]);
        f32x2 o;
        o[0] = pcen_out(v[i][0], m0);
        o[1] = pcen_out(v[i][1], m1);
        __builtin_nontemporal_store(o, op + (size_t)i * (FF / 2));
    }
}

// ---- fallback (ws too small): R2-style warm-up kernel, known-good ----
__global__ __launch_bounds__(128) void pcen_fallback(const float* __restrict__ x,
                                                     float* __restrict__ out) {
    const int job = blockIdx.x;
    const int b   = job >> 5;
    const int k   = job & 31;
    const int f   = threadIdx.x;
    const int t0  = k * 256;
    const size_t base = ((size_t)b * TT + t0) * FF + f;
    const float* xp = x + base;
    float*       op = out + base;
    float m;
    if (k == 0) {
        float xv = xp[0];
        m = xv;
        op[0] = pcen_out(xv, m);
    } else {
        const float* wp = xp - (size_t)256 * FF;
        m = wp[0];
        #pragma unroll 8
        for (int j = 1; j < 256; ++j) m = fmaf(AA, m, SS * wp[(size_t)j * FF]);
        float xv = xp[0];
        m = fmaf(AA, m, SS * xv);
        op[0] = pcen_out(xv, m);
    }
    #pragma unroll 4
    for (int j = 1; j < 256; ++j) {
        float xv = xp[(size_t)j * FF];
        m = fmaf(AA, m, SS * xv);
        op[(size_t)j * FF] = pcen_out(xv, m);
    }
}

extern "C" void kernel_launch(void* const* d_in, const int* in_sizes, int n_in,
                              void* d_out, int out_size, void* d_ws, size_t ws_size,
                              hipStream_t stream) {
    const float* x = (const float*)d_in[0];
    float* out = (float*)d_out;
    (void)in_sizes; (void)n_in; (void)out_size;

    const size_t q_bytes = (size_t)BB * KC * FF * sizeof(float);  // 2 MB
    if (ws_size >= q_bytes) {
        float* q = (float*)d_ws;
        pcen_k1<<<BB * KC, 256, 0, stream>>>(x, q);
        pcen_k3<<<BB * KC, 256, 0, stream>>>(x, q, out);
    } else {
        pcen_fallback<<<BB * 32, 128, 0, stream>>>(x, out);
    }
}